// Round 1
// baseline (351.290 us; speedup 1.0000x reference)
//
#include <hip/hip_runtime.h>
#include <stdint.h>

#define NUM_CLASSES 21
// ws layout: [0..20]=t_cnt, [21..41]=p_cnt, [42..62]=inter
#define WS_INTS (3 * NUM_CLASSES)

#define TILE_PIX 256
#define TILE_FLOATS (TILE_PIX * NUM_CLASSES)   // 5376 floats = 21504 B per tensor
#define CHUNKS 21                              // 1 KiB (64 lanes x 16 B) chunks per tensor tile

__global__ void zero_ws_kernel(unsigned int* ws) {
    int i = threadIdx.x;
    if (i < WS_INTS) ws[i] = 0u;
}

// Async global->LDS copy of one 1 KiB chunk: 64 lanes x 16 B, contiguous.
// LDS dest is wave-uniform base (+ lane*16 done by HW); global src is per-lane.
__device__ __forceinline__ void async_copy_1k(const float* __restrict__ g, float* l, int lane) {
    __builtin_amdgcn_global_load_lds(
        (const __attribute__((address_space(1))) void*)(g + lane * 4),
        (__attribute__((address_space(3))) void*)l,
        16, 0, 0);
}

__global__ __launch_bounds__(256, 3) void hist_kernel(const float* __restrict__ yt,
                                                      const float* __restrict__ yp,
                                                      unsigned int* __restrict__ ws,
                                                      long long npix) {
    __shared__ float ldsT[TILE_FLOATS];
    __shared__ float ldsP[TILE_FLOATS];
    __shared__ unsigned int h[WS_INTS];

    const int tid  = threadIdx.x;
    const int wid  = tid >> 6;
    const int lane = tid & 63;

    for (int i = tid; i < WS_INTS; i += 256) h[i] = 0u;

    const long long ntiles = npix >> 8;   // full 256-pixel tiles (8192 for this shape)

    for (long long tile = blockIdx.x; tile < ntiles; tile += gridDim.x) {
        const long long fbase = tile * (long long)TILE_FLOATS;

        // ---- async stage: 42 contiguous 1 KiB chunks (21 per tensor), split across 4 waves.
        // Each instruction moves 1024 contiguous bytes = 16 cache lines (minimum possible).
        for (int c = wid; c < 2 * CHUNKS; c += 4) {
            if (c < CHUNKS)
                async_copy_1k(yt + fbase + (long long)c * 256,            ldsT + c * 256,            lane);
            else
                async_copy_1k(yp + fbase + (long long)(c - CHUNKS) * 256, ldsP + (c - CHUNKS) * 256, lane);
        }
        __syncthreads();   // compiler drains vmcnt(0) before s_barrier -> LDS tile ready

        // ---- per-thread 21-class argmax out of LDS.
        // Read stride = 21 floats; gcd(21,32)=1 -> 2 lanes/bank across wave64 = conflict-free.
        const float* tp = ldsT + tid * NUM_CLASSES;
        const float* pp = ldsP + tid * NUM_CLASSES;
        float tb = tp[0]; int ti = 0;
        float pb = pp[0]; int pi = 0;
#pragma unroll
        for (int c = 1; c < NUM_CLASSES; ++c) {
            float tv = tp[c];
            float pv = pp[c];
            if (tv > tb) { tb = tv; ti = c; }   // strict > == jnp.argmax first-max ties
            if (pv > pb) { pb = pv; pi = c; }
        }
        atomicAdd(&h[ti], 1u);
        atomicAdd(&h[NUM_CLASSES + pi], 1u);
        if (ti == pi) atomicAdd(&h[2 * NUM_CLASSES + ti], 1u);

        __syncthreads();   // protect LDS tile before next iteration overwrites it
    }

    // ---- tail pixels (npix % 256 != 0) — not taken for 8*512*512; block 0, direct global.
    if (blockIdx.x == 0) {
        for (long long pix = ntiles * TILE_PIX + tid; pix < npix; pix += 256) {
            const float* t = yt + pix * NUM_CLASSES;
            const float* p = yp + pix * NUM_CLASSES;
            float tb = t[0], pb = p[0];
            int ti = 0, pi = 0;
            for (int c = 1; c < NUM_CLASSES; ++c) {
                if (t[c] > tb) { tb = t[c]; ti = c; }
                if (p[c] > pb) { pb = p[c]; pi = c; }
            }
            atomicAdd(&h[ti], 1u);
            atomicAdd(&h[NUM_CLASSES + pi], 1u);
            if (ti == pi) atomicAdd(&h[2 * NUM_CLASSES + ti], 1u);
        }
    }

    __syncthreads();
    for (int i = tid; i < WS_INTS; i += 256) {
        if (h[i]) atomicAdd(&ws[i], h[i]);
    }
}

__global__ void finalize_kernel(const unsigned int* __restrict__ ws,
                                float* __restrict__ out) {
    int c = threadIdx.x;  // one wave
    float iou = 0.0f, valid = 0.0f;
    if (c < NUM_CLASSES) {
        float inter = (float)ws[2 * NUM_CLASSES + c];
        float uni   = (float)ws[c] + (float)ws[NUM_CLASSES + c] - inter;
        if (uni > 0.0f) { iou = inter / uni; valid = 1.0f; }
    }
#pragma unroll
    for (int off = 32; off > 0; off >>= 1) {
        iou   += __shfl_down(iou, off);
        valid += __shfl_down(valid, off);
    }
    if (c == 0) out[0] = iou / valid;
}

extern "C" void kernel_launch(void* const* d_in, const int* in_sizes, int n_in,
                              void* d_out, int out_size, void* d_ws, size_t ws_size,
                              hipStream_t stream) {
    const float* y_true = (const float*)d_in[0];
    const float* y_pred = (const float*)d_in[1];
    float* out = (float*)d_out;
    unsigned int* ws = (unsigned int*)d_ws;

    long long total = (long long)in_sizes[0];   // 44,040,192
    long long npix  = total / NUM_CLASSES;      // 2,097,152

    int block = 256;
    int grid  = 768;   // 3 blocks/CU (LDS-bound at ~43.3 KB/block), grid-stride over 8192 tiles

    zero_ws_kernel<<<1, 64, 0, stream>>>(ws);
    hist_kernel<<<grid, block, 0, stream>>>(y_true, y_pred, ws, npix);
    finalize_kernel<<<1, 64, 0, stream>>>(ws, out);
}